// Round 13
// baseline (143.048 us; speedup 1.0000x reference)
//
#include <hip/hip_runtime.h>
#include <hip/hip_bf16.h>

#define DEVFN __device__ __forceinline__

typedef float f32x4 __attribute__((ext_vector_type(4)));
typedef float f32x16 __attribute__((ext_vector_type(16)));
typedef __bf16 bf16x8 __attribute__((ext_vector_type(8)));
typedef unsigned short u16x8 __attribute__((ext_vector_type(8)));
typedef unsigned short u16x4 __attribute__((ext_vector_type(4)));
typedef unsigned u32x4 __attribute__((ext_vector_type(4)));

DEVFN unsigned short f2bf(float f) {
  unsigned u = __builtin_bit_cast(unsigned, f);
  u = (u + 0x7FFFu + ((u >> 16) & 1u)) >> 16;  // RNE
  return (unsigned short)u;
}

DEVFN f32x4 mfma_bf16(u16x8 a, u16x8 b, f32x4 c) {
  return __builtin_amdgcn_mfma_f32_16x16x32_bf16((bf16x8)a, (bf16x8)b, c, 0, 0, 0);
}

DEVFN f32x16 mfma32(u16x8 a, u16x8 b, f32x16 c) {
  return __builtin_amdgcn_mfma_f32_32x32x16_bf16((bf16x8)a, (bf16x8)b, c, 0, 0, 0);
}

DEVFN unsigned cvt_pk_bf16(float a, float b) {
  unsigned r;
  asm("v_cvt_pk_bf16_f32 %0, %1, %2" : "=v"(r) : "v"(a), "v"(b));
  return r;  // a in [15:0], b in [31:16]
}

// v_permlane32_swap_b32: a' = {a[0:31], b[0:31]}, b' = {a[32:63], b[32:63]}
DEVFN void permswap(unsigned& a, unsigned& b) {
  asm("v_permlane32_swap_b32 %0, %1" : "+v"(a), "+v"(b));
}

// sin/cos of (rev * 2*pi) via HW trans ops; rev >= 0.
DEVFN void sincos_rev(float rev, float* sn, float* cs) {
  float fr, s, c;
  asm("v_fract_f32 %0, %1" : "=v"(fr) : "v"(rev));
  asm("v_sin_f32 %0, %1" : "=v"(s) : "v"(fr));
  asm("v_cos_f32 %0, %1" : "=v"(c) : "v"(fr));
  *sn = s; *cs = c;
}

DEVFN void gload_lds16(const void* g, void* l) {
  __builtin_amdgcn_global_load_lds(
      (const __attribute__((address_space(1))) void*)g,
      (__attribute__((address_space(3))) void*)l, 16, 0, 0);
}

// ---------- 1. LayerNorm on strided rows -> xs bf16 [B*Ts][D] ----------
__global__ __launch_bounds__(256) void ln_stride_kernel(
    const float* __restrict__ x, const float* __restrict__ w,
    const float* __restrict__ bb, unsigned short* __restrict__ xs,
    int T, int Ts, int D, int stride) {
  int row = blockIdx.x;  // B*Ts rows
  int b = row / Ts, ts = row - b * Ts;
  const float* xr = x + ((size_t)b * T + (size_t)ts * stride) * D;
  int t = threadIdx.x;
  float4 v = *(const float4*)(xr + t * 4);
  float s = v.x + v.y + v.z + v.w;
  float sq = v.x * v.x + v.y * v.y + v.z * v.z + v.w * v.w;
#pragma unroll
  for (int m = 1; m < 64; m <<= 1) { s += __shfl_xor(s, m); sq += __shfl_xor(sq, m); }
  __shared__ float ps[4], pq[4];
  if ((t & 63) == 0) { ps[t >> 6] = s; pq[t >> 6] = sq; }
  __syncthreads();
  s = ps[0] + ps[1] + ps[2] + ps[3];
  sq = pq[0] + pq[1] + pq[2] + pq[3];
  float invD = 1.0f / (float)D;
  float mu = s * invD;
  float var = sq * invD - mu * mu;
  float rs = rsqrtf(var + 1e-5f);
  int c = t * 4;
  float4 wv = *(const float4*)(w + c);
  float4 bv = *(const float4*)(bb + c);
  u16x4 o;
  o[0] = f2bf((v.x - mu) * rs * wv.x + bv.x);
  o[1] = f2bf((v.y - mu) * rs * wv.y + bv.y);
  o[2] = f2bf((v.z - mu) * rs * wv.z + bv.z);
  o[3] = f2bf((v.w - mu) * rs * wv.w + bv.w);
  *(u16x4*)(xs + (size_t)row * D + c) = o;
}

// ---------- 2. W [K][N] f32 -> Wt [N][K] bf16 ----------
__global__ __launch_bounds__(256) void wconv_kernel(
    const float* __restrict__ W, unsigned short* __restrict__ Wt, int K, int N) {
  __shared__ float tile[32][33];
  int n0 = blockIdx.x * 32, k0 = blockIdx.y * 32;
  int tx = threadIdx.x & 31, ty = threadIdx.x >> 5;
#pragma unroll
  for (int i = 0; i < 32; i += 8) tile[ty + i][tx] = W[(size_t)(k0 + ty + i) * N + n0 + tx];
  __syncthreads();
#pragma unroll
  for (int i = 0; i < 32; i += 8) Wt[(size_t)(n0 + ty + i) * K + k0 + tx] = f2bf(tile[tx][ty + i]);
}

// ---------- 3. QKV GEMM: 256x128 tile, BK=32, ring-3 LDS, counted vmcnt ----
// Grid 16bm x 24bn = 384 blocks, 512 threads (8 waves = 4M x 2N, 64x64 each).
// LDS ring-3 x 24KB = 72KB -> 2 blocks/CU co-resident (TLP covers barriers).
// Stage(t+2) issued after top barrier (slot t-1's reads barrier-protected);
// boundary waits s_waitcnt vmcnt(3) (stage t+1 stays in flight).
// XCD map: xcd -> 4bm x 12bn sub-grid; per-K-slice set 160KB -> L2 hits.
__global__ __launch_bounds__(512, 1) void gemm_qkv256_kernel(
    const unsigned short* __restrict__ A, const unsigned short* __restrict__ Bt,
    const float* __restrict__ bias, int M, int N, int Kd,
    unsigned short* __restrict__ Qo, unsigned short* __restrict__ Ko,
    unsigned short* __restrict__ Vt) {
  __shared__ __align__(128) char lds[73728];   // 3 x (A 16KB | B 8KB)
  const int tid = threadIdx.x, l = tid & 63, w = tid >> 6;
  const int wr = w >> 1, wc = w & 1;       // 4M x 2N waves
  const int lg = l >> 4, lr = l & 15;
  const int o = blockIdx.x;
  const int xcd = o & 7, s = o >> 3;            // s in 0..47
  const int bm = (xcd >> 1) * 4 + (s & 3);      // 0..15
  const int bn = (xcd & 1) * 12 + (s >> 2);     // 0..23
  const int m0 = bm << 8, n0 = bn << 7;
  const int chk = (lg ^ ((lr >> 1) & 3)) << 4;  // read chunk byte offset

  f32x4 acc[4][4] = {};

  // stage K-slice kk (A 16KB: 2 chunks/thread; B 8KB: 1 chunk/thread)
#define STAGE32(kk, bufoff)                                                 \
  do {                                                                      \
    _Pragma("unroll")                                                       \
    for (int i_ = 0; i_ < 2; i_++) {                                        \
      int c_ = tid + (i_ << 9);                                             \
      int rl_ = c_ >> 2, c4_ = c_ & 3;                                      \
      int cs_ = c4_ ^ ((rl_ >> 1) & 3);                                     \
      gload_lds16(A + (size_t)(m0 + rl_) * Kd + (kk) + cs_ * 8,             \
                  lds + (bufoff) + c_ * 16);                                \
    }                                                                       \
    {                                                                       \
      int c_ = tid;                                                         \
      int rl_ = c_ >> 2, c4_ = c_ & 3;                                      \
      int cs_ = c4_ ^ ((rl_ >> 1) & 3);                                     \
      gload_lds16(Bt + (size_t)(n0 + rl_) * Kd + (kk) + cs_ * 8,            \
                  lds + (bufoff) + 16384 + c_ * 16);                        \
    }                                                                       \
  } while (0)

  // prologue: 2 tiles in flight
  STAGE32(0, 0);
  STAGE32(32, 24576);

  const int NT = Kd >> 5;  // 32
  for (int t = 0; t < NT; ++t) {
    // counted boundary wait: stage(t) done, stage(t+1) stays outstanding
    if (t < NT - 1) asm volatile("s_waitcnt vmcnt(3)" ::: "memory");
    else            asm volatile("s_waitcnt vmcnt(0)" ::: "memory");
    __builtin_amdgcn_s_barrier();   // all waves' stage(t) landed
    const int curoff = (t % 3) * 24576;

    u16x8 bfr[4], afr[4];
#pragma unroll
    for (int nf = 0; nf < 4; nf++)
      bfr[nf] = *(const u16x8*)(lds + curoff + 16384 +
                                (wc * 64 + nf * 16 + lr) * 64 + chk);
#pragma unroll
    for (int mf = 0; mf < 4; mf++)
      afr[mf] = *(const u16x8*)(lds + curoff +
                                (wr * 64 + mf * 16 + lr) * 64 + chk);
    if (t + 2 < NT) STAGE32((t + 2) << 5, ((t + 2) % 3) * 24576);
    asm volatile("s_waitcnt lgkmcnt(0)" ::: "memory");
    __builtin_amdgcn_sched_barrier(0);
    __builtin_amdgcn_s_setprio(1);
#pragma unroll
    for (int mf = 0; mf < 4; mf++)
#pragma unroll
      for (int nf = 0; nf < 4; nf++)
        acc[mf][nf] = mfma_bf16(afr[mf], bfr[nf], acc[mf][nf]);
    __builtin_amdgcn_s_setprio(0);
    __builtin_amdgcn_s_barrier();   // all waves done reading slot t
  }
#undef STAGE32

  // ---- epilogue: bias + RoPE scatter (Q pre-scaled), K, V blocked ----
  int nb = n0 + wc * 64;       // 64-aligned -> exactly one (which, head)
  int which = nb >> 10;        // 0=q 1=k 2=v
  int h = (nb & 1023) >> 6;
  if (which < 2) {
    unsigned short* dst = (which == 0) ? Qo : Ko;
    float qsc = (which == 0) ? 0.18033688f : 1.0f;  // 0.125 * log2(e)
#pragma unroll
    for (int nt = 0; nt < 2; nt++) {
      int d = nt * 16 + lr;
      float invf_rev = exp2f((float)d * -0.41524101f) * 0.15915494f;
      float blo = bias[nb + nt * 16 + lr];
      float bhi = bias[nb + (nt + 2) * 16 + lr];
#pragma unroll
      for (int mt = 0; mt < 4; mt++) {
        int mb = m0 + wr * 64 + mt * 16 + lg * 4;
#pragma unroll
        for (int r = 0; r < 4; r++) {
          int m = mb + r;
          int b_ = m >> 10, ts = m & 1023;
          float va = acc[mt][nt][r] + blo;
          float vb = acc[mt][nt + 2][r] + bhi;
          float sn, cs;
          sincos_rev((float)ts * invf_rev, &sn, &cs);
          size_t base = (((size_t)(b_ * 16 + h)) * 1024 + ts) * 64;
          dst[base + d] = f2bf((va * cs - vb * sn) * qsc);
          dst[base + d + 32] = f2bf((vb * cs + va * sn) * qsc);
        }
      }
    }
  } else {
    // V blocked: [bh][tile=ts>>5][d=64][kv=32]
#pragma unroll
    for (int nt = 0; nt < 4; nt++) {
      int d = nt * 16 + lr;
      float bi = bias[nb + nt * 16 + lr];
#pragma unroll
      for (int mt = 0; mt < 4; mt++) {
        int mb = m0 + wr * 64 + mt * 16 + lg * 4;
        int b_ = mb >> 10, tsb = mb & 1023;
        u16x4 pk;
#pragma unroll
        for (int r = 0; r < 4; r++) pk[r] = f2bf(acc[mt][nt][r] + bi);
        *(u16x4*)(Vt + (size_t)(b_ * 16 + h) * 65536 +
                  (size_t)(tsb >> 5) * 2048 + d * 32 + (tsb & 31)) = pk;
      }
    }
  }
}

// ---------- 5. out-proj GEMM: 128x128, 2-phase dbuf ----------
__global__ __launch_bounds__(256) void gemm_out_kernel(
    const unsigned short* __restrict__ A, const unsigned short* __restrict__ Bt,
    const float* __restrict__ bias, int M, int N, int Kd,
    float* __restrict__ Co) {
  constexpr int BK = 32;
  __shared__ unsigned short As[2][128 * BK];
  __shared__ unsigned short Bs[2][128 * BK];
  int nbm = M >> 7;
  int bm = blockIdx.x % nbm, bn = blockIdx.x / nbm;
  int m0 = bm << 7, n0 = bn << 7;
  int t = threadIdx.x, l = t & 63, w = t >> 6;
  int wr = w >> 1, wc = w & 1;
  int lg = l >> 4, lr = l & 15;

  f32x4 acc[4][4] = {};
  int srow = t >> 2, scol = (t & 3) * 8;
  const unsigned short* gA = A + (size_t)(m0 + srow) * Kd + scol;
  const unsigned short* gB = Bt + (size_t)(n0 + srow) * Kd + scol;

#define STAGE_G(buf, kk)                                          \
  do {                                                            \
    unsigned short* la_ = &As[buf][t * 8];                        \
    unsigned short* lb_ = &Bs[buf][t * 8];                        \
    gload_lds16(gA + (kk), la_);                                  \
    gload_lds16(gA + (kk) + (size_t)64 * Kd, la_ + 64 * BK);      \
    gload_lds16(gB + (kk), lb_);                                  \
    gload_lds16(gB + (kk) + (size_t)64 * Kd, lb_ + 64 * BK);      \
  } while (0)

  STAGE_G(0, 0);
  __syncthreads();
  int cur = 0;
  for (int k0 = 0; k0 < Kd; k0 += BK) {
    bool more = (k0 + BK < Kd);
    if (more) STAGE_G(cur ^ 1, k0 + BK);
    u16x8 af[4], bf[4];
#pragma unroll
    for (int i = 0; i < 4; i++) {
      af[i] = *(const u16x8*)(&As[cur][(wr * 64 + i * 16 + lr) * BK + lg * 8]);
      bf[i] = *(const u16x8*)(&Bs[cur][(wc * 64 + i * 16 + lr) * BK + lg * 8]);
    }
#pragma unroll
    for (int i = 0; i < 4; i++)
#pragma unroll
      for (int j = 0; j < 4; j++) acc[i][j] = mfma_bf16(af[i], bf[j], acc[i][j]);
    if (more) __syncthreads();
    cur ^= 1;
  }
#undef STAGE_G

#pragma unroll
  for (int nt = 0; nt < 4; nt++) {
    int n = n0 + wc * 64 + nt * 16 + lr;
    float bi = bias[n];
#pragma unroll
    for (int mt = 0; mt < 4; mt++) {
      int mb = m0 + wr * 64 + mt * 16 + lg * 4;
#pragma unroll
      for (int r = 0; r < 4; r++) Co[(size_t)(mb + r) * N + n] = acc[mt][nt][r] + bi;
    }
  }
}

// ---------- 4. causal flash attention, cooperative LDS-staged K/V ----------
// (unchanged from round 11: fused kv-64 softmax, permswap, setprio)
__global__ __launch_bounds__(256) void attn_kernel(
    const unsigned short* __restrict__ Q, const unsigned short* __restrict__ K,
    const unsigned short* __restrict__ Vt, unsigned short* __restrict__ O,
    int Ts, int H) {
  __shared__ __align__(128) char kvlds[2][16384];  // [buf][K 8KB | V 8KB]
  int t = threadIdx.x, w = t >> 6, l = t & 63;
  int h2 = l >> 5, lq = l & 31;
  int bh = blockIdx.x & 63;
  int i = blockIdx.x >> 6;
  int qg = (i < 4) ? 7 - i : i - 4;  // pairs (7,0),(6,1),(5,2),(4,3) per CU
  int b = bh / H, hh = bh % H;
  int qw0 = qg * 128 + w * 32;       // this wave's 32 q rows

  const unsigned short* Qh = Q + ((size_t)bh * Ts) * 64;
  const unsigned short* Kh = K + ((size_t)bh * Ts) * 64;
  const unsigned short* Vh = Vt + (size_t)bh * 65536;

  u16x8 qf[4];
#pragma unroll
  for (int c = 0; c < 4; c++)
    qf[c] = *(const u16x8*)(Qh + (size_t)(qw0 + lq) * 64 + c * 16 + h2 * 8);

#define STAGE_KV(jt, buf)                                                   \
  do {                                                                      \
    _Pragma("unroll")                                                       \
    for (int i_ = 0; i_ < 2; i_++) {                                        \
      int c_ = t + (i_ << 8);                                               \
      int r_ = c_ >> 3, jg_ = c_ & 7;                                       \
      gload_lds16(Kh + (size_t)(jt) * 4096 + r_ * 64 + ((jg_ ^ (r_ & 7)) << 3), \
                  kvlds[buf] + c_ * 16);                                    \
    }                                                                       \
    {                                                                       \
      int d_ = t >> 2, g_ = t & 3;                                          \
      int gs_ = (g_ ^ ((d_ >> 1) & 3)) << 3;                                \
      gload_lds16(Vh + (size_t)(2 * (jt)) * 2048 + d_ * 32 + gs_,           \
                  kvlds[buf] + 8192 + t * 16);                              \
      gload_lds16(Vh + (size_t)(2 * (jt) + 1) * 2048 + d_ * 32 + gs_,       \
                  kvlds[buf] + 12288 + t * 16);                             \
    }                                                                       \
  } while (0)

  f32x16 olo = {}, ohi = {};
  float mrow = -1e30f, lsum = 0.f;   // lsum PER-HALF (merged at end)
  const int sk = lq & 7;             // K read swizzle
  const int sv = (lq >> 1) & 3;      // V read swizzle

  int ntiles = 2 * qg + 2;
  STAGE_KV(0, 0);

  for (int jt = 0; jt < ntiles; jt++) {
    __syncthreads();
    int cur = jt & 1;
    if (jt + 1 < ntiles) STAGE_KV(jt + 1, cur ^ 1);

    int kvt = jt * 64;
    if (kvt > qw0) continue;           // wave-uniform; barrier still met next iter
    bool haveS1 = (kvt + 32 <= qw0);   // wave-uniform
    bool diag0 = (kvt == qw0);         // implies !haveS1
    bool diag1 = (kvt + 32 == qw0);    // implies haveS1

    // ---- QK^T for both subtiles, MFMAs back-to-back ----
    const char* kb0 = kvlds[cur] + lq * 128;
    const char* kb1 = kvlds[cur] + (32 + lq) * 128;
    u16x8 kf0[4], kf1[4];
#pragma unroll
    for (int c = 0; c < 4; c++)
      kf0[c] = *(const u16x8*)(kb0 + (((c << 1) + h2) ^ sk) * 16);
    f32x16 sA = {}, sB = {};
    if (haveS1) {
#pragma unroll
      for (int c = 0; c < 4; c++)
        kf1[c] = *(const u16x8*)(kb1 + (((c << 1) + h2) ^ sk) * 16);
      __builtin_amdgcn_s_setprio(1);
#pragma unroll
      for (int c = 0; c < 4; c++) sA = mfma32(kf0[c], qf[c], sA);
#pragma unroll
      for (int c = 0; c < 4; c++) sB = mfma32(kf1[c], qf[c], sB);
      __builtin_amdgcn_s_setprio(0);
    } else {
      __builtin_amdgcn_s_setprio(1);
#pragma unroll
      for (int c = 0; c < 4; c++) sA = mfma32(kf0[c], qf[c], sA);
      __builtin_amdgcn_s_setprio(0);
    }

    // ---- p[32]: both subtiles, causal masks ----
    float p[32];
#pragma unroll
    for (int r = 0; r < 16; r++) {
      float v = sA[r];
      if (diag0) {
        int kvl = (r & 3) + 8 * (r >> 2) + 4 * h2;
        v = (kvl > lq) ? -1e30f : v;
      }
      p[r] = v;
    }
#pragma unroll
    for (int r = 0; r < 16; r++) {
      float v = haveS1 ? sB[r] : -1e30f;
      if (diag1) {
        int kvl = (r & 3) + 8 * (r >> 2) + 4 * h2;
        v = (kvl > lq) ? -1e30f : v;
      }
      p[16 + r] = v;
    }

    // ---- ONE fused softmax pass over 64 kv ----
    float m16[16], m8[8], m4[4];
#pragma unroll
    for (int r = 0; r < 16; r++) m16[r] = fmaxf(p[r], p[16 + r]);
#pragma unroll
    for (int r = 0; r < 8; r++) m8[r] = fmaxf(m16[r], m16[r + 8]);
#pragma unroll
    for (int r = 0; r < 4; r++) m4[r] = fmaxf(m8[r], m8[r + 4]);
    float tmax = fmaxf(fmaxf(m4[0], m4[2]), fmaxf(m4[1], m4[3]));
    tmax = fmaxf(tmax, __shfl_xor(tmax, 32));

    if (!__all(tmax <= mrow + 8.0f)) {   // T13 defer-max
      float mnew = fmaxf(mrow, tmax);
      float al = exp2f(mrow - mnew);
      mrow = mnew;
      lsum *= al;
      olo *= al;
      ohi *= al;
    }

#pragma unroll
    for (int r = 0; r < 32; r++) p[r] = exp2f(p[r] - mrow);
    float s16[16], s8[8], s4[4];
#pragma unroll
    for (int r = 0; r < 16; r++) s16[r] = p[r] + p[16 + r];
#pragma unroll
    for (int r = 0; r < 8; r++) s8[r] = s16[r] + s16[r + 8];
#pragma unroll
    for (int r = 0; r < 4; r++) s4[r] = s8[r] + s8[r + 4];
    lsum += (s4[0] + s4[2]) + (s4[1] + s4[3]);

    // ---- subtile A fragments via cvt_pk + permswap (T12) ----
    {
      unsigned a01 = cvt_pk_bf16(p[0], p[1]),   a23 = cvt_pk_bf16(p[2], p[3]);
      unsigned a45 = cvt_pk_bf16(p[4], p[5]),   a67 = cvt_pk_bf16(p[6], p[7]);
      unsigned a89 = cvt_pk_bf16(p[8], p[9]),   aAB = cvt_pk_bf16(p[10], p[11]);
      unsigned aCD = cvt_pk_bf16(p[12], p[13]), aEF = cvt_pk_bf16(p[14], p[15]);
      permswap(a01, a45);
      permswap(a23, a67);
      permswap(a89, aCD);
      permswap(aAB, aEF);
      u32x4 f0 = {a01, a23, a45, a67};
      u32x4 f1 = {a89, aAB, aCD, aEF};
      u16x8 P0 = __builtin_bit_cast(u16x8, f0);
      u16x8 P1 = __builtin_bit_cast(u16x8, f1);

      const char* vb_ = kvlds[cur] + 8192;
      u16x8 vf[4];
      vf[0] = *(const u16x8*)(vb_ + lq * 64 + ((0 + h2) ^ sv) * 16);
      vf[1] = *(const u16x8*)(vb_ + lq * 64 + ((2 + h2) ^ sv) * 16);
      vf[2] = *(const u16x8*)(vb_ + (32 + lq) * 64 + ((0 + h2) ^ sv) * 16);
      vf[3] = *(const u16x8*)(vb_ + (32 + lq) * 64 + ((2 + h2) ^ sv) * 16);
      __builtin_amdgcn_s_setprio(1);
      olo = mfma32(vf[0], P0, olo);
      olo = mfma32(vf[1], P1, olo);
      ohi = mfma32(vf[2], P0, ohi);
      ohi = mfma32(vf[3], P1, ohi);
      __builtin_amdgcn_s_setprio(0);
    }

    // ---- subtile B (only when valid) ----
    if (haveS1) {
      unsigned b01 = cvt_pk_bf16(p[16], p[17]), b23 = cvt_pk_bf16(p[18], p[19]);
      unsigned b45 = cvt_pk_bf16(p[20], p[21]), b67 = cvt_pk_bf16(p[22], p[23]);
      unsigned b89 = cvt_pk_bf16(p[24], p[25]), bAB = cvt_pk_bf16(p[26], p[27]);
      unsigned bCD = cvt_pk_bf16(p[28], p[29]), bEF = cvt_pk_bf16(p[30], p[31]);
      permswap(b01, b45);
      permswap(b23, b67);
      permswap(b89, bCD);
      permswap(bAB, bEF);
      u32x4 g0 = {b01, b23, b45, b67};
      u32x4 g1 = {b89, bAB, bCD, bEF};
      u16x8 Q0 = __builtin_bit_cast(u16x8, g0);
      u16x8 Q1 = __builtin_bit_cast(u16x8, g1);

      const char* vb_ = kvlds[cur] + 8192 + 4096;
      u16x8 vf[4];
      vf[0] = *(const u16x8*)(vb_ + lq * 64 + ((0 + h2) ^ sv) * 16);
      vf[1] = *(const u16x8*)(vb_ + lq * 64 + ((2 + h2) ^ sv) * 16);
      vf[2] = *(const u16x8*)(vb_ + (32 + lq) * 64 + ((0 + h2) ^ sv) * 16);
      vf[3] = *(const u16x8*)(vb_ + (32 + lq) * 64 + ((2 + h2) ^ sv) * 16);
      __builtin_amdgcn_s_setprio(1);
      olo = mfma32(vf[0], Q0, olo);
      olo = mfma32(vf[1], Q1, olo);
      ohi = mfma32(vf[2], Q0, ohi);
      ohi = mfma32(vf[3], Q1, ohi);
      __builtin_amdgcn_s_setprio(0);
    }
  }
#undef STAGE_KV

  lsum += __shfl_xor(lsum, 32);  // cross-half merge (deferred)
  float inv = 1.0f / lsum;
  int q = qw0 + lq;
  unsigned short* orow = O + ((size_t)b * Ts + q) * (size_t)(H * 64) + hh * 64;
#pragma unroll
  for (int g = 0; g < 4; g++) {
    u16x4 plo, phi;
#pragma unroll
    for (int j2 = 0; j2 < 4; j2++) {
      plo[j2] = f2bf(olo[g * 4 + j2] * inv);   // d = j2 + 8g + 4h2
      phi[j2] = f2bf(ohi[g * 4 + j2] * inv);   // d = 32 + j2 + 8g + 4h2
    }
    *(u16x4*)(orow + g * 8 + h2 * 4) = plo;
    *(u16x4*)(orow + 32 + g * 8 + h2 * 4) = phi;
  }
}

// ---------- 6. upsample + residual, STRIDE=4 structured ----------
__global__ __launch_bounds__(256) void upsample_kernel(
    const float* __restrict__ x, const float* __restrict__ proj,
    float* __restrict__ out, int T, int Ts, int D) {
  int bk = blockIdx.x;
  int b = bk / Ts, k = bk - b * Ts;
  int d4 = threadIdx.x;              // D/4 = 256
  size_t prow = (size_t)b * Ts * D;
  const f32x4 a = *((const f32x4*)(proj + prow + (size_t)max(k - 1, 0) * D) + d4);
  const f32x4 bb = *((const f32x4*)(proj + prow + (size_t)k * D) + d4);
  const f32x4 c = *((const f32x4*)(proj + prow + (size_t)min(k + 1, Ts - 1) * D) + d4);

  size_t xbase = ((size_t)b * T + 4 * (size_t)k) * D + (size_t)d4 * 4;
  f32x4 x0 = __builtin_nontemporal_load((const f32x4*)(x + xbase));
  f32x4 x1 = __builtin_nontemporal_load((const f32x4*)(x + xbase + D));
  f32x4 x2 = __builtin_nontemporal_load((const f32x4*)(x + xbase + 2 * D));
  f32x4 x3 = __builtin_nontemporal_load((const f32x4*)(x + xbase + 3 * D));

  f32x4 o0 = x0 + 0.375f * a + 0.625f * bb;   // j=0: src=k-0.375
  f32x4 o1 = x1 + 0.125f * a + 0.875f * bb;   // j=1: src=k-0.125
  f32x4 o2 = x2 + 0.875f * bb + 0.125f * c;   // j=2: src=k+0.125
  f32x4 o3 = x3 + 0.625f * bb + 0.375f * c;   // j=3: src=k+0.375

  __builtin_nontemporal_store(o0, (f32x4*)(out + xbase));
  __builtin_nontemporal_store(o1, (f32x4*)(out + xbase + D));
  __builtin_nontemporal_store(o2, (f32x4*)(out + xbase + 2 * D));
  __builtin_nontemporal_store(o3, (f32x4*)(out + xbase + 3 * D));
}

extern "C" void kernel_launch(void* const* d_in, const int* in_sizes, int n_in,
                              void* d_out, int out_size, void* d_ws, size_t ws_size,
                              hipStream_t stream) {
  (void)in_sizes; (void)n_in; (void)out_size; (void)ws_size;
  const float* x = (const float*)d_in[0];
  const float* norm_w = (const float*)d_in[1];
  const float* norm_b = (const float*)d_in[2];
  const float* W_qkv = (const float*)d_in[3];
  const float* b_qkv = (const float*)d_in[4];
  const float* W_out = (const float*)d_in[5];
  const float* b_out = (const float*)d_in[6];
  float* out = (float*)d_out;

  const int B = 4, T = 4096, D = 1024, H = 16, STR = 4;
  const int Ts = T / STR;   // 1024
  const int M = B * Ts;     // 4096

  char* ws = (char*)d_ws;
  unsigned short* xs  = (unsigned short*)(ws);                      // 8 MiB, reused as att_out
  unsigned short* Wtq = (unsigned short*)(ws + ((size_t)8 << 20));  // 6 MiB
  unsigned short* Wto = (unsigned short*)(ws + ((size_t)14 << 20)); // 2 MiB
  unsigned short* Qb  = (unsigned short*)(ws + ((size_t)16 << 20)); // 8 MiB
  unsigned short* Kb  = (unsigned short*)(ws + ((size_t)24 << 20)); // 8 MiB
  unsigned short* Vtb = (unsigned short*)(ws + ((size_t)32 << 20)); // 8 MiB
  float* proj         = (float*)(ws + ((size_t)16 << 20));          // 16 MiB, overlays Q/K (dead)
  unsigned short* att = xs;                                         // overlays xs (dead)

  ln_stride_kernel<<<M, 256, 0, stream>>>(x, norm_w, norm_b, xs, T, Ts, D, STR);
  wconv_kernel<<<dim3(3 * D / 32, D / 32), 256, 0, stream>>>(W_qkv, Wtq, D, 3 * D);
  wconv_kernel<<<dim3(D / 32, D / 32), 256, 0, stream>>>(W_out, Wto, D, D);
  gemm_qkv256_kernel<<<(M / 256) * (3 * D / 128), 512, 0, stream>>>(
      xs, Wtq, b_qkv, M, 3 * D, D, Qb, Kb, Vtb);
  attn_kernel<<<B * H * 8, 256, 0, stream>>>(Qb, Kb, Vtb, att, Ts, H);
  gemm_out_kernel<<<(M / 128) * (D / 128), 256, 0, stream>>>(
      att, Wto, b_out, M, D, D, proj);
  upsample_kernel<<<B * Ts, 256, 0, stream>>>(x, proj, out, T, Ts, D);
}

// Round 14
// 127.987 us; speedup vs baseline: 1.1177x; 1.1177x over previous
//
#include <hip/hip_runtime.h>
#include <hip/hip_bf16.h>

#define DEVFN __device__ __forceinline__

typedef float f32x4 __attribute__((ext_vector_type(4)));
typedef float f32x16 __attribute__((ext_vector_type(16)));
typedef __bf16 bf16x8 __attribute__((ext_vector_type(8)));
typedef unsigned short u16x8 __attribute__((ext_vector_type(8)));
typedef unsigned short u16x4 __attribute__((ext_vector_type(4)));
typedef unsigned u32x4 __attribute__((ext_vector_type(4)));

DEVFN unsigned short f2bf(float f) {
  unsigned u = __builtin_bit_cast(unsigned, f);
  u = (u + 0x7FFFu + ((u >> 16) & 1u)) >> 16;  // RNE
  return (unsigned short)u;
}

DEVFN f32x4 mfma_bf16(u16x8 a, u16x8 b, f32x4 c) {
  return __builtin_amdgcn_mfma_f32_16x16x32_bf16((bf16x8)a, (bf16x8)b, c, 0, 0, 0);
}

DEVFN f32x16 mfma32(u16x8 a, u16x8 b, f32x16 c) {
  return __builtin_amdgcn_mfma_f32_32x32x16_bf16((bf16x8)a, (bf16x8)b, c, 0, 0, 0);
}

DEVFN unsigned cvt_pk_bf16(float a, float b) {
  unsigned r;
  asm("v_cvt_pk_bf16_f32 %0, %1, %2" : "=v"(r) : "v"(a), "v"(b));
  return r;  // a in [15:0], b in [31:16]
}

// v_permlane32_swap_b32: a' = {a[0:31], b[0:31]}, b' = {a[32:63], b[32:63]}
DEVFN void permswap(unsigned& a, unsigned& b) {
  asm("v_permlane32_swap_b32 %0, %1" : "+v"(a), "+v"(b));
}

// sin/cos of (rev * 2*pi) via HW trans ops; rev >= 0.
DEVFN void sincos_rev(float rev, float* sn, float* cs) {
  float fr, s, c;
  asm("v_fract_f32 %0, %1" : "=v"(fr) : "v"(rev));
  asm("v_sin_f32 %0, %1" : "=v"(s) : "v"(fr));
  asm("v_cos_f32 %0, %1" : "=v"(c) : "v"(fr));
  *sn = s; *cs = c;
}

DEVFN void gload_lds16(const void* g, void* l) {
  __builtin_amdgcn_global_load_lds(
      (const __attribute__((address_space(1))) void*)g,
      (__attribute__((address_space(3))) void*)l, 16, 0, 0);
}

// ---------- 1. LayerNorm on strided rows -> xs bf16 [B*Ts][D] ----------
__global__ __launch_bounds__(256) void ln_stride_kernel(
    const float* __restrict__ x, const float* __restrict__ w,
    const float* __restrict__ bb, unsigned short* __restrict__ xs,
    int T, int Ts, int D, int stride) {
  int row = blockIdx.x;  // B*Ts rows
  int b = row / Ts, ts = row - b * Ts;
  const float* xr = x + ((size_t)b * T + (size_t)ts * stride) * D;
  int t = threadIdx.x;
  float4 v = *(const float4*)(xr + t * 4);
  float s = v.x + v.y + v.z + v.w;
  float sq = v.x * v.x + v.y * v.y + v.z * v.z + v.w * v.w;
#pragma unroll
  for (int m = 1; m < 64; m <<= 1) { s += __shfl_xor(s, m); sq += __shfl_xor(sq, m); }
  __shared__ float ps[4], pq[4];
  if ((t & 63) == 0) { ps[t >> 6] = s; pq[t >> 6] = sq; }
  __syncthreads();
  s = ps[0] + ps[1] + ps[2] + ps[3];
  sq = pq[0] + pq[1] + pq[2] + pq[3];
  float invD = 1.0f / (float)D;
  float mu = s * invD;
  float var = sq * invD - mu * mu;
  float rs = rsqrtf(var + 1e-5f);
  int c = t * 4;
  float4 wv = *(const float4*)(w + c);
  float4 bv = *(const float4*)(bb + c);
  u16x4 o;
  o[0] = f2bf((v.x - mu) * rs * wv.x + bv.x);
  o[1] = f2bf((v.y - mu) * rs * wv.y + bv.y);
  o[2] = f2bf((v.z - mu) * rs * wv.z + bv.z);
  o[3] = f2bf((v.w - mu) * rs * wv.w + bv.w);
  *(u16x4*)(xs + (size_t)row * D + c) = o;
}

// ---------- 2. W [K][N] f32 -> Wt [N][K] bf16 ----------
__global__ __launch_bounds__(256) void wconv_kernel(
    const float* __restrict__ W, unsigned short* __restrict__ Wt, int K, int N) {
  __shared__ float tile[32][33];
  int n0 = blockIdx.x * 32, k0 = blockIdx.y * 32;
  int tx = threadIdx.x & 31, ty = threadIdx.x >> 5;
#pragma unroll
  for (int i = 0; i < 32; i += 8) tile[ty + i][tx] = W[(size_t)(k0 + ty + i) * N + n0 + tx];
  __syncthreads();
#pragma unroll
  for (int i = 0; i < 32; i += 8) Wt[(size_t)(n0 + ty + i) * K + k0 + tx] = f2bf(tile[tx][ty + i]);
}

// ---------- 3. QKV GEMM: 256x256, BK=32, 4-deep ring, counted vmcnt, ------
// single phase/tile, XCD panel-tiled (round-12 exact — reverted from r13).
__global__ __launch_bounds__(512, 1) void gemm_qkv256_kernel(
    const unsigned short* __restrict__ A, const unsigned short* __restrict__ Bt,
    const float* __restrict__ bias, int M, int N, int Kd,
    unsigned short* __restrict__ Qo, unsigned short* __restrict__ Ko,
    unsigned short* __restrict__ Vt) {
  __shared__ __align__(128) char lds[131072];
  const int tid = threadIdx.x, l = tid & 63, w = tid >> 6;
  const int wr = w >> 2, wc = w & 3;       // 2M x 4N waves
  const int lg = l >> 4, lr = l & 15;
  const int o = blockIdx.x;
  const int xcd = o & 7, s = o >> 3;       // s in 0..23
  const int bm = (xcd & 3) * 4 + (s & 3);
  const int bn = (xcd >> 2) * 6 + (s >> 2);
  const int m0 = bm << 8, n0 = bn << 8;
  const int chk = (lg ^ ((lr >> 1) & 3)) << 4;  // read chunk byte offset

  f32x4 acc[8][4] = {};

#define STAGE32(kk, bufoff)                                                 \
  do {                                                                      \
    _Pragma("unroll")                                                       \
    for (int i_ = 0; i_ < 2; i_++) {                                        \
      int c_ = tid + (i_ << 9);                                             \
      int rl_ = c_ >> 2, c4_ = c_ & 3;                                      \
      int cs_ = c4_ ^ ((rl_ >> 1) & 3);                                     \
      gload_lds16(A + (size_t)(m0 + rl_) * Kd + (kk) + cs_ * 8,             \
                  lds + (bufoff) + c_ * 16);                                \
      gload_lds16(Bt + (size_t)(n0 + rl_) * Kd + (kk) + cs_ * 8,            \
                  lds + (bufoff) + 16384 + c_ * 16);                        \
    }                                                                       \
  } while (0)

  STAGE32(0, 0);
  STAGE32(32, 32768);
  STAGE32(64, 65536);

  const int NT = Kd >> 5;  // 32
  for (int t = 0; t < NT; ++t) {
    if (t < NT - 2)       asm volatile("s_waitcnt vmcnt(8)" ::: "memory");
    else if (t == NT - 2) asm volatile("s_waitcnt vmcnt(4)" ::: "memory");
    else                  asm volatile("s_waitcnt vmcnt(0)" ::: "memory");
    __builtin_amdgcn_s_barrier();   // all waves' stage(t) landed
    const int curoff = (t & 3) << 15;

    u16x8 bfr[4], afr[8];
#pragma unroll
    for (int nf = 0; nf < 4; nf++)
      bfr[nf] = *(const u16x8*)(lds + curoff + 16384 +
                                (wc * 64 + nf * 16 + lr) * 64 + chk);
#pragma unroll
    for (int mf = 0; mf < 8; mf++)
      afr[mf] = *(const u16x8*)(lds + curoff +
                                (wr * 128 + mf * 16 + lr) * 64 + chk);
    if (t + 3 < NT) STAGE32((t + 3) << 5, ((t + 3) & 3) << 15);
    asm volatile("s_waitcnt lgkmcnt(0)" ::: "memory");
    __builtin_amdgcn_sched_barrier(0);
    __builtin_amdgcn_s_setprio(1);
#pragma unroll
    for (int mf = 0; mf < 8; mf++)
#pragma unroll
      for (int nf = 0; nf < 4; nf++)
        acc[mf][nf] = mfma_bf16(afr[mf], bfr[nf], acc[mf][nf]);
    __builtin_amdgcn_s_setprio(0);
    __builtin_amdgcn_s_barrier();   // all waves done reading slot t
  }
#undef STAGE32

  int nb = n0 + wc * 64;
  int which = nb >> 10;        // 0=q 1=k 2=v
  int h = (nb & 1023) >> 6;
  if (which < 2) {
    unsigned short* dst = (which == 0) ? Qo : Ko;
    float qsc = (which == 0) ? 0.18033688f : 1.0f;  // 0.125 * log2(e)
#pragma unroll
    for (int nt = 0; nt < 2; nt++) {
      int d = nt * 16 + lr;
      float invf_rev = exp2f((float)d * -0.41524101f) * 0.15915494f;
      float blo = bias[nb + nt * 16 + lr];
      float bhi = bias[nb + (nt + 2) * 16 + lr];
#pragma unroll
      for (int mt = 0; mt < 8; mt++) {
        int mb = m0 + wr * 128 + mt * 16 + lg * 4;
#pragma unroll
        for (int r = 0; r < 4; r++) {
          int m = mb + r;
          int b_ = m >> 10, ts = m & 1023;
          float va = acc[mt][nt][r] + blo;
          float vb = acc[mt][nt + 2][r] + bhi;
          float sn, cs;
          sincos_rev((float)ts * invf_rev, &sn, &cs);
          size_t base = (((size_t)(b_ * 16 + h)) * 1024 + ts) * 64;
          dst[base + d] = f2bf((va * cs - vb * sn) * qsc);
          dst[base + d + 32] = f2bf((vb * cs + va * sn) * qsc);
        }
      }
    }
  } else {
    // V blocked: [bh][tile=ts>>5][d=64][kv=32]
#pragma unroll
    for (int nt = 0; nt < 4; nt++) {
      int d = nt * 16 + lr;
      float bi = bias[nb + nt * 16 + lr];
#pragma unroll
      for (int mt = 0; mt < 8; mt++) {
        int mb = m0 + wr * 128 + mt * 16 + lg * 4;
        int b_ = mb >> 10, tsb = mb & 1023;
        u16x4 pk;
#pragma unroll
        for (int r = 0; r < 4; r++) pk[r] = f2bf(acc[mt][nt][r] + bi);
        *(u16x4*)(Vt + (size_t)(b_ * 16 + h) * 65536 +
                  (size_t)(tsb >> 5) * 2048 + d * 32 + (tsb & 31)) = pk;
      }
    }
  }
}

// ---------- 5. out-proj GEMM: 128x128, BK=32, ring-3, counted vmcnt -------
// Port of the proven round-12 QKV structure: single phase/tile, counted
// vmcnt(4) boundary (stage t+1 stays in flight), setprio, XCD panel map
// (xcd owns bm-group of 4 x all 8 bn -> A 1MB + B 2MB <= L2).
__global__ __launch_bounds__(256) void gemm_out_kernel(
    const unsigned short* __restrict__ A, const unsigned short* __restrict__ Bt,
    const float* __restrict__ bias, int M, int N, int Kd,
    float* __restrict__ Co) {
  __shared__ __align__(128) char lds[49152];   // 3 x (A 8KB | B 8KB)
  const int tid = threadIdx.x, l = tid & 63, w = tid >> 6;
  const int wr = w >> 1, wc = w & 1;       // 2M x 2N waves, 64x64 each
  const int lg = l >> 4, lr = l & 15;
  const int o = blockIdx.x;
  const int xcd = o & 7, s = o >> 3;       // s in 0..31
  const int bm = xcd * 4 + (s & 3);        // 0..31
  const int bn = s >> 2;                   // 0..7
  const int m0 = bm << 7, n0 = bn << 7;
  const int chk = (lg ^ ((lr >> 1) & 3)) << 4;

#define STAGE32O(kk, bufoff)                                                \
  do {                                                                      \
    _Pragma("unroll")                                                       \
    for (int i_ = 0; i_ < 2; i_++) {                                        \
      int c_ = tid + (i_ << 8);                                             \
      int rl_ = c_ >> 2, c4_ = c_ & 3;                                      \
      int cs_ = c4_ ^ ((rl_ >> 1) & 3);                                     \
      gload_lds16(A + (size_t)(m0 + rl_) * Kd + (kk) + cs_ * 8,             \
                  lds + (bufoff) + c_ * 16);                                \
      gload_lds16(Bt + (size_t)(n0 + rl_) * Kd + (kk) + cs_ * 8,            \
                  lds + (bufoff) + 8192 + c_ * 16);                         \
    }                                                                       \
  } while (0)

  f32x4 acc[4][4] = {};
  STAGE32O(0, 0);
  STAGE32O(32, 16384);

  const int NT = Kd >> 5;  // 32
  for (int t = 0; t < NT; ++t) {
    if (t < NT - 1) asm volatile("s_waitcnt vmcnt(4)" ::: "memory");
    else            asm volatile("s_waitcnt vmcnt(0)" ::: "memory");
    __builtin_amdgcn_s_barrier();
    const int curoff = (t % 3) * 16384;

    u16x8 bfr[4], afr[4];
#pragma unroll
    for (int nf = 0; nf < 4; nf++)
      bfr[nf] = *(const u16x8*)(lds + curoff + 8192 +
                                (wc * 64 + nf * 16 + lr) * 64 + chk);
#pragma unroll
    for (int mf = 0; mf < 4; mf++)
      afr[mf] = *(const u16x8*)(lds + curoff +
                                (wr * 64 + mf * 16 + lr) * 64 + chk);
    if (t + 2 < NT) STAGE32O((t + 2) << 5, ((t + 2) % 3) * 16384);
    asm volatile("s_waitcnt lgkmcnt(0)" ::: "memory");
    __builtin_amdgcn_sched_barrier(0);
    __builtin_amdgcn_s_setprio(1);
#pragma unroll
    for (int mf = 0; mf < 4; mf++)
#pragma unroll
      for (int nf = 0; nf < 4; nf++)
        acc[mf][nf] = mfma_bf16(afr[mf], bfr[nf], acc[mf][nf]);
    __builtin_amdgcn_s_setprio(0);
    __builtin_amdgcn_s_barrier();
  }
#undef STAGE32O

#pragma unroll
  for (int nt = 0; nt < 4; nt++) {
    int n = n0 + wc * 64 + nt * 16 + lr;
    float bi = bias[n];
#pragma unroll
    for (int mt = 0; mt < 4; mt++) {
      int mb = m0 + wr * 64 + mt * 16 + lg * 4;
#pragma unroll
      for (int r = 0; r < 4; r++) Co[(size_t)(mb + r) * N + n] = acc[mt][nt][r] + bi;
    }
  }
}

// ---------- 4. causal flash attention, cooperative LDS-staged K/V ----------
// (unchanged from round 11: fused kv-64 softmax, permswap, setprio)
__global__ __launch_bounds__(256) void attn_kernel(
    const unsigned short* __restrict__ Q, const unsigned short* __restrict__ K,
    const unsigned short* __restrict__ Vt, unsigned short* __restrict__ O,
    int Ts, int H) {
  __shared__ __align__(128) char kvlds[2][16384];  // [buf][K 8KB | V 8KB]
  int t = threadIdx.x, w = t >> 6, l = t & 63;
  int h2 = l >> 5, lq = l & 31;
  int bh = blockIdx.x & 63;
  int i = blockIdx.x >> 6;
  int qg = (i < 4) ? 7 - i : i - 4;  // pairs (7,0),(6,1),(5,2),(4,3) per CU
  int b = bh / H, hh = bh % H;
  int qw0 = qg * 128 + w * 32;       // this wave's 32 q rows

  const unsigned short* Qh = Q + ((size_t)bh * Ts) * 64;
  const unsigned short* Kh = K + ((size_t)bh * Ts) * 64;
  const unsigned short* Vh = Vt + (size_t)bh * 65536;

  u16x8 qf[4];
#pragma unroll
  for (int c = 0; c < 4; c++)
    qf[c] = *(const u16x8*)(Qh + (size_t)(qw0 + lq) * 64 + c * 16 + h2 * 8);

#define STAGE_KV(jt, buf)                                                   \
  do {                                                                      \
    _Pragma("unroll")                                                       \
    for (int i_ = 0; i_ < 2; i_++) {                                        \
      int c_ = t + (i_ << 8);                                               \
      int r_ = c_ >> 3, jg_ = c_ & 7;                                       \
      gload_lds16(Kh + (size_t)(jt) * 4096 + r_ * 64 + ((jg_ ^ (r_ & 7)) << 3), \
                  kvlds[buf] + c_ * 16);                                    \
    }                                                                       \
    {                                                                       \
      int d_ = t >> 2, g_ = t & 3;                                          \
      int gs_ = (g_ ^ ((d_ >> 1) & 3)) << 3;                                \
      gload_lds16(Vh + (size_t)(2 * (jt)) * 2048 + d_ * 32 + gs_,           \
                  kvlds[buf] + 8192 + t * 16);                              \
      gload_lds16(Vh + (size_t)(2 * (jt) + 1) * 2048 + d_ * 32 + gs_,       \
                  kvlds[buf] + 12288 + t * 16);                             \
    }                                                                       \
  } while (0)

  f32x16 olo = {}, ohi = {};
  float mrow = -1e30f, lsum = 0.f;   // lsum PER-HALF (merged at end)
  const int sk = lq & 7;             // K read swizzle
  const int sv = (lq >> 1) & 3;      // V read swizzle

  int ntiles = 2 * qg + 2;
  STAGE_KV(0, 0);

  for (int jt = 0; jt < ntiles; jt++) {
    __syncthreads();
    int cur = jt & 1;
    if (jt + 1 < ntiles) STAGE_KV(jt + 1, cur ^ 1);

    int kvt = jt * 64;
    if (kvt > qw0) continue;           // wave-uniform; barrier still met next iter
    bool haveS1 = (kvt + 32 <= qw0);   // wave-uniform
    bool diag0 = (kvt == qw0);         // implies !haveS1
    bool diag1 = (kvt + 32 == qw0);    // implies haveS1

    // ---- QK^T for both subtiles, MFMAs back-to-back ----
    const char* kb0 = kvlds[cur] + lq * 128;
    const char* kb1 = kvlds[cur] + (32 + lq) * 128;
    u16x8 kf0[4], kf1[4];
#pragma unroll
    for (int c = 0; c < 4; c++)
      kf0[c] = *(const u16x8*)(kb0 + (((c << 1) + h2) ^ sk) * 16);
    f32x16 sA = {}, sB = {};
    if (haveS1) {
#pragma unroll
      for (int c = 0; c < 4; c++)
        kf1[c] = *(const u16x8*)(kb1 + (((c << 1) + h2) ^ sk) * 16);
      __builtin_amdgcn_s_setprio(1);
#pragma unroll
      for (int c = 0; c < 4; c++) sA = mfma32(kf0[c], qf[c], sA);
#pragma unroll
      for (int c = 0; c < 4; c++) sB = mfma32(kf1[c], qf[c], sB);
      __builtin_amdgcn_s_setprio(0);
    } else {
      __builtin_amdgcn_s_setprio(1);
#pragma unroll
      for (int c = 0; c < 4; c++) sA = mfma32(kf0[c], qf[c], sA);
      __builtin_amdgcn_s_setprio(0);
    }

    // ---- p[32]: both subtiles, causal masks ----
    float p[32];
#pragma unroll
    for (int r = 0; r < 16; r++) {
      float v = sA[r];
      if (diag0) {
        int kvl = (r & 3) + 8 * (r >> 2) + 4 * h2;
        v = (kvl > lq) ? -1e30f : v;
      }
      p[r] = v;
    }
#pragma unroll
    for (int r = 0; r < 16; r++) {
      float v = haveS1 ? sB[r] : -1e30f;
      if (diag1) {
        int kvl = (r & 3) + 8 * (r >> 2) + 4 * h2;
        v = (kvl > lq) ? -1e30f : v;
      }
      p[16 + r] = v;
    }

    // ---- ONE fused softmax pass over 64 kv ----
    float m16[16], m8[8], m4[4];
#pragma unroll
    for (int r = 0; r < 16; r++) m16[r] = fmaxf(p[r], p[16 + r]);
#pragma unroll
    for (int r = 0; r < 8; r++) m8[r] = fmaxf(m16[r], m16[r + 8]);
#pragma unroll
    for (int r = 0; r < 4; r++) m4[r] = fmaxf(m8[r], m8[r + 4]);
    float tmax = fmaxf(fmaxf(m4[0], m4[2]), fmaxf(m4[1], m4[3]));
    tmax = fmaxf(tmax, __shfl_xor(tmax, 32));

    if (!__all(tmax <= mrow + 8.0f)) {   // T13 defer-max
      float mnew = fmaxf(mrow, tmax);
      float al = exp2f(mrow - mnew);
      mrow = mnew;
      lsum *= al;
      olo *= al;
      ohi *= al;
    }

#pragma unroll
    for (int r = 0; r < 32; r++) p[r] = exp2f(p[r] - mrow);
    float s16[16], s8[8], s4[4];
#pragma unroll
    for (int r = 0; r < 16; r++) s16[r] = p[r] + p[16 + r];
#pragma unroll
    for (int r = 0; r < 8; r++) s8[r] = s16[r] + s16[r + 8];
#pragma unroll
    for (int r = 0; r < 4; r++) s4[r] = s8[r] + s8[r + 4];
    lsum += (s4[0] + s4[2]) + (s4[1] + s4[3]);

    // ---- subtile A fragments via cvt_pk + permswap (T12) ----
    {
      unsigned a01 = cvt_pk_bf16(p[0], p[1]),   a23 = cvt_pk_bf16(p[2], p[3]);
      unsigned a45 = cvt_pk_bf16(p[4], p[5]),   a67 = cvt_pk_bf16(p[6], p[7]);
      unsigned a89 = cvt_pk_bf16(p[8], p[9]),   aAB = cvt_pk_bf16(p[10], p[11]);
      unsigned aCD = cvt_pk_bf16(p[12], p[13]), aEF = cvt_pk_bf16(p[14], p[15]);
      permswap(a01, a45);
      permswap(a23, a67);
      permswap(a89, aCD);
      permswap(aAB, aEF);
      u32x4 f0 = {a01, a23, a45, a67};
      u32x4 f1 = {a89, aAB, aCD, aEF};
      u16x8 P0 = __builtin_bit_cast(u16x8, f0);
      u16x8 P1 = __builtin_bit_cast(u16x8, f1);

      const char* vb_ = kvlds[cur] + 8192;
      u16x8 vf[4];
      vf[0] = *(const u16x8*)(vb_ + lq * 64 + ((0 + h2) ^ sv) * 16);
      vf[1] = *(const u16x8*)(vb_ + lq * 64 + ((2 + h2) ^ sv) * 16);
      vf[2] = *(const u16x8*)(vb_ + (32 + lq) * 64 + ((0 + h2) ^ sv) * 16);
      vf[3] = *(const u16x8*)(vb_ + (32 + lq) * 64 + ((2 + h2) ^ sv) * 16);
      __builtin_amdgcn_s_setprio(1);
      olo = mfma32(vf[0], P0, olo);
      olo = mfma32(vf[1], P1, olo);
      ohi = mfma32(vf[2], P0, ohi);
      ohi = mfma32(vf[3], P1, ohi);
      __builtin_amdgcn_s_setprio(0);
    }

    // ---- subtile B (only when valid) ----
    if (haveS1) {
      unsigned b01 = cvt_pk_bf16(p[16], p[17]), b23 = cvt_pk_bf16(p[18], p[19]);
      unsigned b45 = cvt_pk_bf16(p[20], p[21]), b67 = cvt_pk_bf16(p[22], p[23]);
      unsigned b89 = cvt_pk_bf16(p[24], p[25]), bAB = cvt_pk_bf16(p[26], p[27]);
      unsigned bCD = cvt_pk_bf16(p[28], p[29]), bEF = cvt_pk_bf16(p[30], p[31]);
      permswap(b01, b45);
      permswap(b23, b67);
      permswap(b89, bCD);
      permswap(bAB, bEF);
      u32x4 g0 = {b01, b23, b45, b67};
      u32x4 g1 = {b89, bAB, bCD, bEF};
      u16x8 Q0 = __builtin_bit_cast(u16x8, g0);
      u16x8 Q1 = __builtin_bit_cast(u16x8, g1);

      const char* vb_ = kvlds[cur] + 8192 + 4096;
      u16x8 vf[4];
      vf[0] = *(const u16x8*)(vb_ + lq * 64 + ((0 + h2) ^ sv) * 16);
      vf[1] = *(const u16x8*)(vb_ + lq * 64 + ((2 + h2) ^ sv) * 16);
      vf[2] = *(const u16x8*)(vb_ + (32 + lq) * 64 + ((0 + h2) ^ sv) * 16);
      vf[3] = *(const u16x8*)(vb_ + (32 + lq) * 64 + ((2 + h2) ^ sv) * 16);
      __builtin_amdgcn_s_setprio(1);
      olo = mfma32(vf[0], Q0, olo);
      olo = mfma32(vf[1], Q1, olo);
      ohi = mfma32(vf[2], Q0, ohi);
      ohi = mfma32(vf[3], Q1, ohi);
      __builtin_amdgcn_s_setprio(0);
    }
  }
#undef STAGE_KV

  lsum += __shfl_xor(lsum, 32);  // cross-half merge (deferred)
  float inv = 1.0f / lsum;
  int q = qw0 + lq;
  unsigned short* orow = O + ((size_t)b * Ts + q) * (size_t)(H * 64) + hh * 64;
#pragma unroll
  for (int g = 0; g < 4; g++) {
    u16x4 plo, phi;
#pragma unroll
    for (int j2 = 0; j2 < 4; j2++) {
      plo[j2] = f2bf(olo[g * 4 + j2] * inv);   // d = j2 + 8g + 4h2
      phi[j2] = f2bf(ohi[g * 4 + j2] * inv);   // d = 32 + j2 + 8g + 4h2
    }
    *(u16x4*)(orow + g * 8 + h2 * 4) = plo;
    *(u16x4*)(orow + 32 + g * 8 + h2 * 4) = phi;
  }
}

// ---------- 6. upsample + residual, STRIDE=4 structured ----------
__global__ __launch_bounds__(256) void upsample_kernel(
    const float* __restrict__ x, const float* __restrict__ proj,
    float* __restrict__ out, int T, int Ts, int D) {
  int bk = blockIdx.x;
  int b = bk / Ts, k = bk - b * Ts;
  int d4 = threadIdx.x;              // D/4 = 256
  size_t prow = (size_t)b * Ts * D;
  const f32x4 a = *((const f32x4*)(proj + prow + (size_t)max(k - 1, 0) * D) + d4);
  const f32x4 bb = *((const f32x4*)(proj + prow + (size_t)k * D) + d4);
  const f32x4 c = *((const f32x4*)(proj + prow + (size_t)min(k + 1, Ts - 1) * D) + d4);

  size_t xbase = ((size_t)b * T + 4 * (size_t)k) * D + (size_t)d4 * 4;
  f32x4 x0 = __builtin_nontemporal_load((const f32x4*)(x + xbase));
  f32x4 x1 = __builtin_nontemporal_load((const f32x4*)(x + xbase + D));
  f32x4 x2 = __builtin_nontemporal_load((const f32x4*)(x + xbase + 2 * D));
  f32x4 x3 = __builtin_nontemporal_load((const f32x4*)(x + xbase + 3 * D));

  f32x4 o0 = x0 + 0.375f * a + 0.625f * bb;   // j=0: src=k-0.375
  f32x4 o1 = x1 + 0.125f * a + 0.875f * bb;   // j=1: src=k-0.125
  f32x4 o2 = x2 + 0.875f * bb + 0.125f * c;   // j=2: src=k+0.125
  f32x4 o3 = x3 + 0.625f * bb + 0.375f * c;   // j=3: src=k+0.375

  __builtin_nontemporal_store(o0, (f32x4*)(out + xbase));
  __builtin_nontemporal_store(o1, (f32x4*)(out + xbase + D));
  __builtin_nontemporal_store(o2, (f32x4*)(out + xbase + 2 * D));
  __builtin_nontemporal_store(o3, (f32x4*)(out + xbase + 3 * D));
}

extern "C" void kernel_launch(void* const* d_in, const int* in_sizes, int n_in,
                              void* d_out, int out_size, void* d_ws, size_t ws_size,
                              hipStream_t stream) {
  (void)in_sizes; (void)n_in; (void)out_size; (void)ws_size;
  const float* x = (const float*)d_in[0];
  const float* norm_w = (const float*)d_in[1];
  const float* norm_b = (const float*)d_in[2];
  const float* W_qkv = (const float*)d_in[3];
  const float* b_qkv = (const float*)d_in[4];
  const float* W_out = (const float*)d_in[5];
  const float* b_out = (const float*)d_in[6];
  float* out = (float*)d_out;

  const int B = 4, T = 4096, D = 1024, H = 16, STR = 4;
  const int Ts = T / STR;   // 1024
  const int M = B * Ts;     // 4096

  char* ws = (char*)d_ws;
  unsigned short* xs  = (unsigned short*)(ws);                      // 8 MiB, reused as att_out
  unsigned short* Wtq = (unsigned short*)(ws + ((size_t)8 << 20));  // 6 MiB
  unsigned short* Wto = (unsigned short*)(ws + ((size_t)14 << 20)); // 2 MiB
  unsigned short* Qb  = (unsigned short*)(ws + ((size_t)16 << 20)); // 8 MiB
  unsigned short* Kb  = (unsigned short*)(ws + ((size_t)24 << 20)); // 8 MiB
  unsigned short* Vtb = (unsigned short*)(ws + ((size_t)32 << 20)); // 8 MiB
  float* proj         = (float*)(ws + ((size_t)16 << 20));          // 16 MiB, overlays Q/K (dead)
  unsigned short* att = xs;                                         // overlays xs (dead)

  ln_stride_kernel<<<M, 256, 0, stream>>>(x, norm_w, norm_b, xs, T, Ts, D, STR);
  wconv_kernel<<<dim3(3 * D / 32, D / 32), 256, 0, stream>>>(W_qkv, Wtq, D, 3 * D);
  wconv_kernel<<<dim3(D / 32, D / 32), 256, 0, stream>>>(W_out, Wto, D, D);
  gemm_qkv256_kernel<<<(M / 256) * (3 * D / 256), 512, 0, stream>>>(
      xs, Wtq, b_qkv, M, 3 * D, D, Qb, Kb, Vtb);
  attn_kernel<<<B * H * 8, 256, 0, stream>>>(Qb, Kb, Vtb, att, Ts, H);
  gemm_out_kernel<<<(M / 128) * (D / 128), 256, 0, stream>>>(
      att, Wto, b_out, M, D, D, proj);
  upsample_kernel<<<B * Ts, 256, 0, stream>>>(x, proj, out, T, Ts, D);
}

// Round 15
// 118.353 us; speedup vs baseline: 1.2087x; 1.0814x over previous
//
#include <hip/hip_runtime.h>
#include <hip/hip_bf16.h>

#define DEVFN __device__ __forceinline__

typedef float f32x4 __attribute__((ext_vector_type(4)));
typedef float f32x16 __attribute__((ext_vector_type(16)));
typedef __bf16 bf16x8 __attribute__((ext_vector_type(8)));
typedef unsigned short u16x8 __attribute__((ext_vector_type(8)));
typedef unsigned short u16x4 __attribute__((ext_vector_type(4)));
typedef unsigned u32x4 __attribute__((ext_vector_type(4)));

DEVFN unsigned short f2bf(float f) {
  unsigned u = __builtin_bit_cast(unsigned, f);
  u = (u + 0x7FFFu + ((u >> 16) & 1u)) >> 16;  // RNE
  return (unsigned short)u;
}

DEVFN float bf2f(unsigned short s) {
  return __builtin_bit_cast(float, (unsigned)s << 16);
}

DEVFN f32x4 mfma_bf16(u16x8 a, u16x8 b, f32x4 c) {
  return __builtin_amdgcn_mfma_f32_16x16x32_bf16((bf16x8)a, (bf16x8)b, c, 0, 0, 0);
}

DEVFN f32x16 mfma32(u16x8 a, u16x8 b, f32x16 c) {
  return __builtin_amdgcn_mfma_f32_32x32x16_bf16((bf16x8)a, (bf16x8)b, c, 0, 0, 0);
}

DEVFN unsigned cvt_pk_bf16(float a, float b) {
  unsigned r;
  asm("v_cvt_pk_bf16_f32 %0, %1, %2" : "=v"(r) : "v"(a), "v"(b));
  return r;  // a in [15:0], b in [31:16]
}

// v_permlane32_swap_b32: a' = {a[0:31], b[0:31]}, b' = {a[32:63], b[32:63]}
DEVFN void permswap(unsigned& a, unsigned& b) {
  asm("v_permlane32_swap_b32 %0, %1" : "+v"(a), "+v"(b));
}

// sin/cos of (rev * 2*pi) via HW trans ops; rev >= 0.
DEVFN void sincos_rev(float rev, float* sn, float* cs) {
  float fr, s, c;
  asm("v_fract_f32 %0, %1" : "=v"(fr) : "v"(rev));
  asm("v_sin_f32 %0, %1" : "=v"(s) : "v"(fr));
  asm("v_cos_f32 %0, %1" : "=v"(c) : "v"(fr));
  *sn = s; *cs = c;
}

DEVFN void gload_lds16(const void* g, void* l) {
  __builtin_amdgcn_global_load_lds(
      (const __attribute__((address_space(1))) void*)g,
      (__attribute__((address_space(3))) void*)l, 16, 0, 0);
}

// ---------- 1. fused prologue: LN (blocks 0..M-1), wconv W_qkv, wconv W_out
// All three are independent; fusing fills the machine instead of serializing.
__global__ __launch_bounds__(256) void prologue_kernel(
    const float* __restrict__ x, const float* __restrict__ w,
    const float* __restrict__ bb, unsigned short* __restrict__ xs,
    const float* __restrict__ Wq, unsigned short* __restrict__ Wtq,
    const float* __restrict__ Wo, unsigned short* __restrict__ Wto,
    int T, int Ts, int D, int stride, int M) {
  __shared__ float tile[32][33];
  __shared__ float ps[4], pq[4];
  int bid = blockIdx.x;
  int t = threadIdx.x;
  if (bid < M) {
    // ----- LayerNorm on strided row -----
    int b = bid / Ts, ts = bid - b * Ts;
    const float* xr = x + ((size_t)b * T + (size_t)ts * stride) * D;
    float4 v = *(const float4*)(xr + t * 4);
    float s = v.x + v.y + v.z + v.w;
    float sq = v.x * v.x + v.y * v.y + v.z * v.z + v.w * v.w;
#pragma unroll
    for (int m = 1; m < 64; m <<= 1) { s += __shfl_xor(s, m); sq += __shfl_xor(sq, m); }
    if ((t & 63) == 0) { ps[t >> 6] = s; pq[t >> 6] = sq; }
    __syncthreads();
    s = ps[0] + ps[1] + ps[2] + ps[3];
    sq = pq[0] + pq[1] + pq[2] + pq[3];
    float invD = 1.0f / (float)D;
    float mu = s * invD;
    float var = sq * invD - mu * mu;
    float rs = rsqrtf(var + 1e-5f);
    int c = t * 4;
    float4 wv = *(const float4*)(w + c);
    float4 bv = *(const float4*)(bb + c);
    u16x4 o;
    o[0] = f2bf((v.x - mu) * rs * wv.x + bv.x);
    o[1] = f2bf((v.y - mu) * rs * wv.y + bv.y);
    o[2] = f2bf((v.z - mu) * rs * wv.z + bv.z);
    o[3] = f2bf((v.w - mu) * rs * wv.w + bv.w);
    *(u16x4*)(xs + (size_t)bid * D + c) = o;
  } else {
    // ----- weight transpose+convert: W [K][N] f32 -> Wt [N][K] bf16 -----
    const float* W; unsigned short* Wt; int N, b2;
    b2 = bid - M;
    if (b2 < (3 * D / 32) * (D / 32)) { W = Wq; Wt = Wtq; N = 3 * D; }
    else { b2 -= (3 * D / 32) * (D / 32); W = Wo; Wt = Wto; N = D; }
    int nb = N / 32;
    int n0 = (b2 % nb) * 32, k0 = (b2 / nb) * 32;
    int tx = t & 31, ty = t >> 5;
#pragma unroll
    for (int i = 0; i < 32; i += 8) tile[ty + i][tx] = W[(size_t)(k0 + ty + i) * N + n0 + tx];
    __syncthreads();
#pragma unroll
    for (int i = 0; i < 32; i += 8) Wt[(size_t)(n0 + ty + i) * D + k0 + tx] = f2bf(tile[tx][ty + i]);
  }
}

// ---------- 3. QKV GEMM: 256x256, BK=32, 4-deep ring, counted vmcnt, ------
// single phase/tile, XCD panel-tiled (round-12 exact).
__global__ __launch_bounds__(512, 1) void gemm_qkv256_kernel(
    const unsigned short* __restrict__ A, const unsigned short* __restrict__ Bt,
    const float* __restrict__ bias, int M, int N, int Kd,
    unsigned short* __restrict__ Qo, unsigned short* __restrict__ Ko,
    unsigned short* __restrict__ Vt) {
  __shared__ __align__(128) char lds[131072];
  const int tid = threadIdx.x, l = tid & 63, w = tid >> 6;
  const int wr = w >> 2, wc = w & 3;       // 2M x 4N waves
  const int lg = l >> 4, lr = l & 15;
  const int o = blockIdx.x;
  const int xcd = o & 7, s = o >> 3;       // s in 0..23
  const int bm = (xcd & 3) * 4 + (s & 3);
  const int bn = (xcd >> 2) * 6 + (s >> 2);
  const int m0 = bm << 8, n0 = bn << 8;
  const int chk = (lg ^ ((lr >> 1) & 3)) << 4;  // read chunk byte offset

  f32x4 acc[8][4] = {};

#define STAGE32(kk, bufoff)                                                 \
  do {                                                                      \
    _Pragma("unroll")                                                       \
    for (int i_ = 0; i_ < 2; i_++) {                                        \
      int c_ = tid + (i_ << 9);                                             \
      int rl_ = c_ >> 2, c4_ = c_ & 3;                                      \
      int cs_ = c4_ ^ ((rl_ >> 1) & 3);                                     \
      gload_lds16(A + (size_t)(m0 + rl_) * Kd + (kk) + cs_ * 8,             \
                  lds + (bufoff) + c_ * 16);                                \
      gload_lds16(Bt + (size_t)(n0 + rl_) * Kd + (kk) + cs_ * 8,            \
                  lds + (bufoff) + 16384 + c_ * 16);                        \
    }                                                                       \
  } while (0)

  STAGE32(0, 0);
  STAGE32(32, 32768);
  STAGE32(64, 65536);

  const int NT = Kd >> 5;  // 32
  for (int t = 0; t < NT; ++t) {
    if (t < NT - 2)       asm volatile("s_waitcnt vmcnt(8)" ::: "memory");
    else if (t == NT - 2) asm volatile("s_waitcnt vmcnt(4)" ::: "memory");
    else                  asm volatile("s_waitcnt vmcnt(0)" ::: "memory");
    __builtin_amdgcn_s_barrier();   // all waves' stage(t) landed
    const int curoff = (t & 3) << 15;

    u16x8 bfr[4], afr[8];
#pragma unroll
    for (int nf = 0; nf < 4; nf++)
      bfr[nf] = *(const u16x8*)(lds + curoff + 16384 +
                                (wc * 64 + nf * 16 + lr) * 64 + chk);
#pragma unroll
    for (int mf = 0; mf < 8; mf++)
      afr[mf] = *(const u16x8*)(lds + curoff +
                                (wr * 128 + mf * 16 + lr) * 64 + chk);
    if (t + 3 < NT) STAGE32((t + 3) << 5, ((t + 3) & 3) << 15);
    asm volatile("s_waitcnt lgkmcnt(0)" ::: "memory");
    __builtin_amdgcn_sched_barrier(0);
    __builtin_amdgcn_s_setprio(1);
#pragma unroll
    for (int mf = 0; mf < 8; mf++)
#pragma unroll
      for (int nf = 0; nf < 4; nf++)
        acc[mf][nf] = mfma_bf16(afr[mf], bfr[nf], acc[mf][nf]);
    __builtin_amdgcn_s_setprio(0);
    __builtin_amdgcn_s_barrier();   // all waves done reading slot t
  }
#undef STAGE32

  int nb = n0 + wc * 64;
  int which = nb >> 10;        // 0=q 1=k 2=v
  int h = (nb & 1023) >> 6;
  if (which < 2) {
    unsigned short* dst = (which == 0) ? Qo : Ko;
    float qsc = (which == 0) ? 0.18033688f : 1.0f;  // 0.125 * log2(e)
#pragma unroll
    for (int nt = 0; nt < 2; nt++) {
      int d = nt * 16 + lr;
      float invf_rev = exp2f((float)d * -0.41524101f) * 0.15915494f;
      float blo = bias[nb + nt * 16 + lr];
      float bhi = bias[nb + (nt + 2) * 16 + lr];
#pragma unroll
      for (int mt = 0; mt < 8; mt++) {
        int mb = m0 + wr * 128 + mt * 16 + lg * 4;
#pragma unroll
        for (int r = 0; r < 4; r++) {
          int m = mb + r;
          int b_ = m >> 10, ts = m & 1023;
          float va = acc[mt][nt][r] + blo;
          float vb = acc[mt][nt + 2][r] + bhi;
          float sn, cs;
          sincos_rev((float)ts * invf_rev, &sn, &cs);
          size_t base = (((size_t)(b_ * 16 + h)) * 1024 + ts) * 64;
          dst[base + d] = f2bf((va * cs - vb * sn) * qsc);
          dst[base + d + 32] = f2bf((vb * cs + va * sn) * qsc);
        }
      }
    }
  } else {
    // V blocked: [bh][tile=ts>>5][d=64][kv=32]
#pragma unroll
    for (int nt = 0; nt < 4; nt++) {
      int d = nt * 16 + lr;
      float bi = bias[nb + nt * 16 + lr];
#pragma unroll
      for (int mt = 0; mt < 8; mt++) {
        int mb = m0 + wr * 128 + mt * 16 + lg * 4;
        int b_ = mb >> 10, tsb = mb & 1023;
        u16x4 pk;
#pragma unroll
        for (int r = 0; r < 4; r++) pk[r] = f2bf(acc[mt][nt][r] + bi);
        *(u16x4*)(Vt + (size_t)(b_ * 16 + h) * 65536 +
                  (size_t)(tsb >> 5) * 2048 + d * 32 + (tsb & 31)) = pk;
      }
    }
  }
}

// ---------- 5. out-proj GEMM: 128x128, BK=32, ring-3, counted vmcnt -------
// Output proj is bf16 now (halves proj traffic; upsample reads bf16).
__global__ __launch_bounds__(256) void gemm_out_kernel(
    const unsigned short* __restrict__ A, const unsigned short* __restrict__ Bt,
    const float* __restrict__ bias, int M, int N, int Kd,
    unsigned short* __restrict__ Co) {
  __shared__ __align__(128) char lds[49152];   // 3 x (A 8KB | B 8KB)
  const int tid = threadIdx.x, l = tid & 63, w = tid >> 6;
  const int wr = w >> 1, wc = w & 1;       // 2M x 2N waves, 64x64 each
  const int lg = l >> 4, lr = l & 15;
  const int o = blockIdx.x;
  const int xcd = o & 7, s = o >> 3;       // s in 0..31
  const int bm = xcd * 4 + (s & 3);        // 0..31
  const int bn = s >> 2;                   // 0..7
  const int m0 = bm << 7, n0 = bn << 7;
  const int chk = (lg ^ ((lr >> 1) & 3)) << 4;

#define STAGE32O(kk, bufoff)                                                \
  do {                                                                      \
    _Pragma("unroll")                                                       \
    for (int i_ = 0; i_ < 2; i_++) {                                        \
      int c_ = tid + (i_ << 8);                                             \
      int rl_ = c_ >> 2, c4_ = c_ & 3;                                      \
      int cs_ = c4_ ^ ((rl_ >> 1) & 3);                                     \
      gload_lds16(A + (size_t)(m0 + rl_) * Kd + (kk) + cs_ * 8,             \
                  lds + (bufoff) + c_ * 16);                                \
      gload_lds16(Bt + (size_t)(n0 + rl_) * Kd + (kk) + cs_ * 8,            \
                  lds + (bufoff) + 8192 + c_ * 16);                         \
    }                                                                       \
  } while (0)

  f32x4 acc[4][4] = {};
  STAGE32O(0, 0);
  STAGE32O(32, 16384);

  const int NT = Kd >> 5;  // 32
  for (int t = 0; t < NT; ++t) {
    if (t < NT - 1) asm volatile("s_waitcnt vmcnt(4)" ::: "memory");
    else            asm volatile("s_waitcnt vmcnt(0)" ::: "memory");
    __builtin_amdgcn_s_barrier();
    const int curoff = (t % 3) * 16384;

    u16x8 bfr[4], afr[4];
#pragma unroll
    for (int nf = 0; nf < 4; nf++)
      bfr[nf] = *(const u16x8*)(lds + curoff + 8192 +
                                (wc * 64 + nf * 16 + lr) * 64 + chk);
#pragma unroll
    for (int mf = 0; mf < 4; mf++)
      afr[mf] = *(const u16x8*)(lds + curoff +
                                (wr * 64 + mf * 16 + lr) * 64 + chk);
    if (t + 2 < NT) STAGE32O((t + 2) << 5, ((t + 2) % 3) * 16384);
    asm volatile("s_waitcnt lgkmcnt(0)" ::: "memory");
    __builtin_amdgcn_sched_barrier(0);
    __builtin_amdgcn_s_setprio(1);
#pragma unroll
    for (int mf = 0; mf < 4; mf++)
#pragma unroll
      for (int nf = 0; nf < 4; nf++)
        acc[mf][nf] = mfma_bf16(afr[mf], bfr[nf], acc[mf][nf]);
    __builtin_amdgcn_s_setprio(0);
    __builtin_amdgcn_s_barrier();
  }
#undef STAGE32O

#pragma unroll
  for (int nt = 0; nt < 4; nt++) {
    int n = n0 + wc * 64 + nt * 16 + lr;
    float bi = bias[n];
#pragma unroll
    for (int mt = 0; mt < 4; mt++) {
      int mb = m0 + wr * 64 + mt * 16 + lg * 4;
#pragma unroll
      for (int r = 0; r < 4; r++)
        Co[(size_t)(mb + r) * N + n] = f2bf(acc[mt][nt][r] + bi);
    }
  }
}

// ---------- 4. causal flash attention, cooperative LDS-staged K/V ----------
// (unchanged from round 11: fused kv-64 softmax, permswap, setprio)
__global__ __launch_bounds__(256) void attn_kernel(
    const unsigned short* __restrict__ Q, const unsigned short* __restrict__ K,
    const unsigned short* __restrict__ Vt, unsigned short* __restrict__ O,
    int Ts, int H) {
  __shared__ __align__(128) char kvlds[2][16384];  // [buf][K 8KB | V 8KB]
  int t = threadIdx.x, w = t >> 6, l = t & 63;
  int h2 = l >> 5, lq = l & 31;
  int bh = blockIdx.x & 63;
  int i = blockIdx.x >> 6;
  int qg = (i < 4) ? 7 - i : i - 4;  // pairs (7,0),(6,1),(5,2),(4,3) per CU
  int b = bh / H, hh = bh % H;
  int qw0 = qg * 128 + w * 32;       // this wave's 32 q rows

  const unsigned short* Qh = Q + ((size_t)bh * Ts) * 64;
  const unsigned short* Kh = K + ((size_t)bh * Ts) * 64;
  const unsigned short* Vh = Vt + (size_t)bh * 65536;

  u16x8 qf[4];
#pragma unroll
  for (int c = 0; c < 4; c++)
    qf[c] = *(const u16x8*)(Qh + (size_t)(qw0 + lq) * 64 + c * 16 + h2 * 8);

#define STAGE_KV(jt, buf)                                                   \
  do {                                                                      \
    _Pragma("unroll")                                                       \
    for (int i_ = 0; i_ < 2; i_++) {                                        \
      int c_ = t + (i_ << 8);                                               \
      int r_ = c_ >> 3, jg_ = c_ & 7;                                       \
      gload_lds16(Kh + (size_t)(jt) * 4096 + r_ * 64 + ((jg_ ^ (r_ & 7)) << 3), \
                  kvlds[buf] + c_ * 16);                                    \
    }                                                                       \
    {                                                                       \
      int d_ = t >> 2, g_ = t & 3;                                          \
      int gs_ = (g_ ^ ((d_ >> 1) & 3)) << 3;                                \
      gload_lds16(Vh + (size_t)(2 * (jt)) * 2048 + d_ * 32 + gs_,           \
                  kvlds[buf] + 8192 + t * 16);                              \
      gload_lds16(Vh + (size_t)(2 * (jt) + 1) * 2048 + d_ * 32 + gs_,       \
                  kvlds[buf] + 12288 + t * 16);                             \
    }                                                                       \
  } while (0)

  f32x16 olo = {}, ohi = {};
  float mrow = -1e30f, lsum = 0.f;   // lsum PER-HALF (merged at end)
  const int sk = lq & 7;             // K read swizzle
  const int sv = (lq >> 1) & 3;      // V read swizzle

  int ntiles = 2 * qg + 2;
  STAGE_KV(0, 0);

  for (int jt = 0; jt < ntiles; jt++) {
    __syncthreads();
    int cur = jt & 1;
    if (jt + 1 < ntiles) STAGE_KV(jt + 1, cur ^ 1);

    int kvt = jt * 64;
    if (kvt > qw0) continue;           // wave-uniform; barrier still met next iter
    bool haveS1 = (kvt + 32 <= qw0);   // wave-uniform
    bool diag0 = (kvt == qw0);         // implies !haveS1
    bool diag1 = (kvt + 32 == qw0);    // implies haveS1

    // ---- QK^T for both subtiles, MFMAs back-to-back ----
    const char* kb0 = kvlds[cur] + lq * 128;
    const char* kb1 = kvlds[cur] + (32 + lq) * 128;
    u16x8 kf0[4], kf1[4];
#pragma unroll
    for (int c = 0; c < 4; c++)
      kf0[c] = *(const u16x8*)(kb0 + (((c << 1) + h2) ^ sk) * 16);
    f32x16 sA = {}, sB = {};
    if (haveS1) {
#pragma unroll
      for (int c = 0; c < 4; c++)
        kf1[c] = *(const u16x8*)(kb1 + (((c << 1) + h2) ^ sk) * 16);
      __builtin_amdgcn_s_setprio(1);
#pragma unroll
      for (int c = 0; c < 4; c++) sA = mfma32(kf0[c], qf[c], sA);
#pragma unroll
      for (int c = 0; c < 4; c++) sB = mfma32(kf1[c], qf[c], sB);
      __builtin_amdgcn_s_setprio(0);
    } else {
      __builtin_amdgcn_s_setprio(1);
#pragma unroll
      for (int c = 0; c < 4; c++) sA = mfma32(kf0[c], qf[c], sA);
      __builtin_amdgcn_s_setprio(0);
    }

    // ---- p[32]: both subtiles, causal masks ----
    float p[32];
#pragma unroll
    for (int r = 0; r < 16; r++) {
      float v = sA[r];
      if (diag0) {
        int kvl = (r & 3) + 8 * (r >> 2) + 4 * h2;
        v = (kvl > lq) ? -1e30f : v;
      }
      p[r] = v;
    }
#pragma unroll
    for (int r = 0; r < 16; r++) {
      float v = haveS1 ? sB[r] : -1e30f;
      if (diag1) {
        int kvl = (r & 3) + 8 * (r >> 2) + 4 * h2;
        v = (kvl > lq) ? -1e30f : v;
      }
      p[16 + r] = v;
    }

    // ---- ONE fused softmax pass over 64 kv ----
    float m16[16], m8[8], m4[4];
#pragma unroll
    for (int r = 0; r < 16; r++) m16[r] = fmaxf(p[r], p[16 + r]);
#pragma unroll
    for (int r = 0; r < 8; r++) m8[r] = fmaxf(m16[r], m16[r + 8]);
#pragma unroll
    for (int r = 0; r < 4; r++) m4[r] = fmaxf(m8[r], m8[r + 4]);
    float tmax = fmaxf(fmaxf(m4[0], m4[2]), fmaxf(m4[1], m4[3]));
    tmax = fmaxf(tmax, __shfl_xor(tmax, 32));

    if (!__all(tmax <= mrow + 8.0f)) {   // T13 defer-max
      float mnew = fmaxf(mrow, tmax);
      float al = exp2f(mrow - mnew);
      mrow = mnew;
      lsum *= al;
      olo *= al;
      ohi *= al;
    }

#pragma unroll
    for (int r = 0; r < 32; r++) p[r] = exp2f(p[r] - mrow);
    float s16[16], s8[8], s4[4];
#pragma unroll
    for (int r = 0; r < 16; r++) s16[r] = p[r] + p[16 + r];
#pragma unroll
    for (int r = 0; r < 8; r++) s8[r] = s16[r] + s16[r + 8];
#pragma unroll
    for (int r = 0; r < 4; r++) s4[r] = s8[r] + s8[r + 4];
    lsum += (s4[0] + s4[2]) + (s4[1] + s4[3]);

    // ---- subtile A fragments via cvt_pk + permswap (T12) ----
    {
      unsigned a01 = cvt_pk_bf16(p[0], p[1]),   a23 = cvt_pk_bf16(p[2], p[3]);
      unsigned a45 = cvt_pk_bf16(p[4], p[5]),   a67 = cvt_pk_bf16(p[6], p[7]);
      unsigned a89 = cvt_pk_bf16(p[8], p[9]),   aAB = cvt_pk_bf16(p[10], p[11]);
      unsigned aCD = cvt_pk_bf16(p[12], p[13]), aEF = cvt_pk_bf16(p[14], p[15]);
      permswap(a01, a45);
      permswap(a23, a67);
      permswap(a89, aCD);
      permswap(aAB, aEF);
      u32x4 f0 = {a01, a23, a45, a67};
      u32x4 f1 = {a89, aAB, aCD, aEF};
      u16x8 P0 = __builtin_bit_cast(u16x8, f0);
      u16x8 P1 = __builtin_bit_cast(u16x8, f1);

      const char* vb_ = kvlds[cur] + 8192;
      u16x8 vf[4];
      vf[0] = *(const u16x8*)(vb_ + lq * 64 + ((0 + h2) ^ sv) * 16);
      vf[1] = *(const u16x8*)(vb_ + lq * 64 + ((2 + h2) ^ sv) * 16);
      vf[2] = *(const u16x8*)(vb_ + (32 + lq) * 64 + ((0 + h2) ^ sv) * 16);
      vf[3] = *(const u16x8*)(vb_ + (32 + lq) * 64 + ((2 + h2) ^ sv) * 16);
      __builtin_amdgcn_s_setprio(1);
      olo = mfma32(vf[0], P0, olo);
      olo = mfma32(vf[1], P1, olo);
      ohi = mfma32(vf[2], P0, ohi);
      ohi = mfma32(vf[3], P1, ohi);
      __builtin_amdgcn_s_setprio(0);
    }

    // ---- subtile B (only when valid) ----
    if (haveS1) {
      unsigned b01 = cvt_pk_bf16(p[16], p[17]), b23 = cvt_pk_bf16(p[18], p[19]);
      unsigned b45 = cvt_pk_bf16(p[20], p[21]), b67 = cvt_pk_bf16(p[22], p[23]);
      unsigned b89 = cvt_pk_bf16(p[24], p[25]), bAB = cvt_pk_bf16(p[26], p[27]);
      unsigned bCD = cvt_pk_bf16(p[28], p[29]), bEF = cvt_pk_bf16(p[30], p[31]);
      permswap(b01, b45);
      permswap(b23, b67);
      permswap(b89, bCD);
      permswap(bAB, bEF);
      u32x4 g0 = {b01, b23, b45, b67};
      u32x4 g1 = {b89, bAB, bCD, bEF};
      u16x8 Q0 = __builtin_bit_cast(u16x8, g0);
      u16x8 Q1 = __builtin_bit_cast(u16x8, g1);

      const char* vb_ = kvlds[cur] + 8192 + 4096;
      u16x8 vf[4];
      vf[0] = *(const u16x8*)(vb_ + lq * 64 + ((0 + h2) ^ sv) * 16);
      vf[1] = *(const u16x8*)(vb_ + lq * 64 + ((2 + h2) ^ sv) * 16);
      vf[2] = *(const u16x8*)(vb_ + (32 + lq) * 64 + ((0 + h2) ^ sv) * 16);
      vf[3] = *(const u16x8*)(vb_ + (32 + lq) * 64 + ((2 + h2) ^ sv) * 16);
      __builtin_amdgcn_s_setprio(1);
      olo = mfma32(vf[0], Q0, olo);
      olo = mfma32(vf[1], Q1, olo);
      ohi = mfma32(vf[2], Q0, ohi);
      ohi = mfma32(vf[3], Q1, ohi);
      __builtin_amdgcn_s_setprio(0);
    }
  }
#undef STAGE_KV

  lsum += __shfl_xor(lsum, 32);  // cross-half merge (deferred)
  float inv = 1.0f / lsum;
  int q = qw0 + lq;
  unsigned short* orow = O + ((size_t)b * Ts + q) * (size_t)(H * 64) + hh * 64;
#pragma unroll
  for (int g = 0; g < 4; g++) {
    u16x4 plo, phi;
#pragma unroll
    for (int j2 = 0; j2 < 4; j2++) {
      plo[j2] = f2bf(olo[g * 4 + j2] * inv);   // d = j2 + 8g + 4h2
      phi[j2] = f2bf(ohi[g * 4 + j2] * inv);   // d = 32 + j2 + 8g + 4h2
    }
    *(u16x4*)(orow + g * 8 + h2 * 4) = plo;
    *(u16x4*)(orow + 32 + g * 8 + h2 * 4) = phi;
  }
}

// ---------- 6. upsample + residual, STRIDE=4 structured, bf16 proj --------
__global__ __launch_bounds__(256) void upsample_kernel(
    const float* __restrict__ x, const unsigned short* __restrict__ proj,
    float* __restrict__ out, int T, int Ts, int D) {
  int bk = blockIdx.x;
  int b = bk / Ts, k = bk - b * Ts;
  int d4 = threadIdx.x;              // D/4 = 256
  size_t prow = (size_t)b * Ts * D;
  u16x4 av = *((const u16x4*)(proj + prow + (size_t)max(k - 1, 0) * D) + d4);
  u16x4 bv = *((const u16x4*)(proj + prow + (size_t)k * D) + d4);
  u16x4 cv = *((const u16x4*)(proj + prow + (size_t)min(k + 1, Ts - 1) * D) + d4);
  f32x4 a, bb, c;
#pragma unroll
  for (int j = 0; j < 4; j++) {
    a[j] = bf2f(av[j]); bb[j] = bf2f(bv[j]); c[j] = bf2f(cv[j]);
  }

  size_t xbase = ((size_t)b * T + 4 * (size_t)k) * D + (size_t)d4 * 4;
  f32x4 x0 = __builtin_nontemporal_load((const f32x4*)(x + xbase));
  f32x4 x1 = __builtin_nontemporal_load((const f32x4*)(x + xbase + D));
  f32x4 x2 = __builtin_nontemporal_load((const f32x4*)(x + xbase + 2 * D));
  f32x4 x3 = __builtin_nontemporal_load((const f32x4*)(x + xbase + 3 * D));

  f32x4 o0 = x0 + 0.375f * a + 0.625f * bb;   // j=0: src=k-0.375
  f32x4 o1 = x1 + 0.125f * a + 0.875f * bb;   // j=1: src=k-0.125
  f32x4 o2 = x2 + 0.875f * bb + 0.125f * c;   // j=2: src=k+0.125
  f32x4 o3 = x3 + 0.625f * bb + 0.375f * c;   // j=3: src=k+0.375

  __builtin_nontemporal_store(o0, (f32x4*)(out + xbase));
  __builtin_nontemporal_store(o1, (f32x4*)(out + xbase + D));
  __builtin_nontemporal_store(o2, (f32x4*)(out + xbase + 2 * D));
  __builtin_nontemporal_store(o3, (f32x4*)(out + xbase + 3 * D));
}

extern "C" void kernel_launch(void* const* d_in, const int* in_sizes, int n_in,
                              void* d_out, int out_size, void* d_ws, size_t ws_size,
                              hipStream_t stream) {
  (void)in_sizes; (void)n_in; (void)out_size; (void)ws_size;
  const float* x = (const float*)d_in[0];
  const float* norm_w = (const float*)d_in[1];
  const float* norm_b = (const float*)d_in[2];
  const float* W_qkv = (const float*)d_in[3];
  const float* b_qkv = (const float*)d_in[4];
  const float* W_out = (const float*)d_in[5];
  const float* b_out = (const float*)d_in[6];
  float* out = (float*)d_out;

  const int B = 4, T = 4096, D = 1024, H = 16, STR = 4;
  const int Ts = T / STR;   // 1024
  const int M = B * Ts;     // 4096

  char* ws = (char*)d_ws;
  unsigned short* xs  = (unsigned short*)(ws);                      // 8 MiB, reused as att_out
  unsigned short* Wtq = (unsigned short*)(ws + ((size_t)8 << 20));  // 6 MiB
  unsigned short* Wto = (unsigned short*)(ws + ((size_t)14 << 20)); // 2 MiB
  unsigned short* Qb  = (unsigned short*)(ws + ((size_t)16 << 20)); // 8 MiB
  unsigned short* Kb  = (unsigned short*)(ws + ((size_t)24 << 20)); // 8 MiB
  unsigned short* Vtb = (unsigned short*)(ws + ((size_t)32 << 20)); // 8 MiB
  unsigned short* proj = (unsigned short*)(ws + ((size_t)16 << 20)); // 8 MiB, overlays Q (dead)
  unsigned short* att = xs;                                         // overlays xs (dead)

  prologue_kernel<<<M + (3 * D / 32) * (D / 32) + (D / 32) * (D / 32), 256, 0, stream>>>(
      x, norm_w, norm_b, xs, W_qkv, Wtq, W_out, Wto, T, Ts, D, STR, M);
  gemm_qkv256_kernel<<<(M / 256) * (3 * D / 256), 512, 0, stream>>>(
      xs, Wtq, b_qkv, M, 3 * D, D, Qb, Kb, Vtb);
  attn_kernel<<<B * H * 8, 256, 0, stream>>>(Qb, Kb, Vtb, att, Ts, H);
  gemm_out_kernel<<<(M / 128) * (D / 128), 256, 0, stream>>>(
      att, Wto, b_out, M, D, D, proj);
  upsample_kernel<<<B * Ts, 256, 0, stream>>>(x, proj, out, T, Ts, D);
}